// Round 2
// baseline (404.170 us; speedup 1.0000x reference)
//
#include <hip/hip_runtime.h>

#define D 128
#define SCH 1024
#define AGGB 2048  // gather blocks (wsplit rides as 128 extra tail blocks)

typedef __attribute__((ext_vector_type(8))) short short8;
typedef __attribute__((ext_vector_type(4))) float floatx4;

// RNE split of fp32 into bf16 hi + bf16 lo (x ~= hi + lo, err ~2^-17 |x|)
__device__ inline void bf16split(float x, ushort& hi, ushort& lo) {
  unsigned u = __float_as_uint(x);
  unsigned rh = (u + 0x7FFFu + ((u >> 16) & 1u)) & 0xFFFF0000u;
  hi = (ushort)(rh >> 16);
  float fl = x - __uint_as_float(rh);
  unsigned ul = __float_as_uint(fl);
  lo = (ushort)((ul + 0x7FFFu + ((ul >> 16) & 1u)) >> 16);
}

// K0: fused front. blocks [0,nbE): degree histograms; block nbE: gvec = g@W3+b3;
// blocks (nbE, nbE+nsb]: split nodes fp32 -> interleaved bf16 hi/lo rows in
// nhl (= d_out h region, row r: ushorts [r*256, r*256+128)=hi, +128=lo).
__global__ void k_front(const int* __restrict__ snd, const int* __restrict__ rcv,
                        int* __restrict__ cs, int* __restrict__ cr, int E, int nbE,
                        const float* __restrict__ g, const float* __restrict__ W3,
                        const float* __restrict__ b3, float* __restrict__ gvec,
                        const float* __restrict__ nodes, ushort* __restrict__ nhl,
                        int n) {
  __shared__ float part[256];
  const int b = blockIdx.x;
  if (b < nbE) {
    const int e = b * 256 + threadIdx.x;
    if (e < E) {
      atomicAdd(cs + snd[e], 1);
      atomicAdd(cr + rcv[e], 1);
    }
    return;
  }
  if (b == nbE) {
    const int j = threadIdx.x & 127, half = threadIdx.x >> 7;
    float acc = 0.f;
    for (int k = half * 64; k < half * 64 + 64; ++k)
      acc = fmaf(g[k], W3[k * D + j], acc);
    part[threadIdx.x] = acc;
    __syncthreads();
    if (threadIdx.x < D) gvec[j] = b3[j] + part[j] + part[j + 128];
    return;
  }
  // nodes split: 16 threads/row, 8 floats/thread
  const int id = (b - nbE - 1) * 256 + threadIdx.x;
  if (id >= n * 16) return;
  const int r = id >> 4, c = (id & 15) * 8;
  const float* gp = nodes + (size_t)r * D + c;
  const float4 v0 = *(const float4*)gp;
  const float4 v1 = *(const float4*)(gp + 4);
  ushort h0, l0, h1, l1, h2, l2, h3, l3;
  ushort* ob = nhl + (size_t)r * 256;
  bf16split(v0.x, h0, l0); bf16split(v0.y, h1, l1);
  bf16split(v0.z, h2, l2); bf16split(v0.w, h3, l3);
  *(ushort4*)(ob + c) = make_ushort4(h0, h1, h2, h3);
  *(ushort4*)(ob + 128 + c) = make_ushort4(l0, l1, l2, l3);
  bf16split(v1.x, h0, l0); bf16split(v1.y, h1, l1);
  bf16split(v1.z, h2, l2); bf16split(v1.w, h3, l3);
  *(ushort4*)(ob + c + 4) = make_ushort4(h0, h1, h2, h3);
  *(ushort4*)(ob + 128 + c + 4) = make_ushort4(l0, l1, l2, l3);
}

// K1: single-pass exclusive scan of cnt -> off, cursor (lookback via atomics).
__global__ void k_scan(const int* __restrict__ cnt, int* __restrict__ bsum,
                       int* __restrict__ off, int* __restrict__ cursor, int n) {
  __shared__ int sh[256];
  __shared__ int red[4];
  const int t = threadIdx.x, b = blockIdx.x;
  const int base = b * SCH + t * 4;
  int4 v = make_int4(0, 0, 0, 0);
  if (base < n) v = *(const int4*)(cnt + base);
  const int s = v.x + v.y + v.z + v.w;
  sh[t] = s;
  __syncthreads();
  for (int st = 1; st < 256; st <<= 1) {
    const int u = (t >= st) ? sh[t - st] : 0;
    __syncthreads();
    sh[t] += u;
    __syncthreads();
  }
  if (t == 255) atomicExch(bsum + b, sh[255] + 1);  // publish (never 0)
  int pre = 0;
  if (t < b) {
    int x = atomicAdd(bsum + t, 0);
    while (x == 0) {
      __builtin_amdgcn_s_sleep(1);
      x = atomicAdd(bsum + t, 0);
    }
    pre = x - 1;
  }
#pragma unroll
  for (int o = 32; o > 0; o >>= 1) pre += __shfl_down(pre, o, 64);
  if ((t & 63) == 0) red[t >> 6] = pre;
  __syncthreads();
  const int gbase = red[0] + red[1] + red[2] + red[3];
  const int ex = sh[t] - s + gbase;
  if (base < n) {
    const int4 o4 = make_int4(ex, ex + v.x, ex + v.x + v.y, ex + v.x + v.y + v.z);
    *(int4*)(off + base) = o4;
    *(int4*)(cursor + base) = o4;
  }
}

// K2: CSR fill (bucket edges by receiver)
__global__ void k_fill(const int* __restrict__ snd, const int* __restrict__ rcv,
                       int* __restrict__ cursor, int* __restrict__ srt, int E) {
  const int e = blockIdx.x * blockDim.x + threadIdx.x;
  if (e < E) {
    const int p = atomicAdd(cursor + rcv[e], 1);
    srt[p] = snd[e];
  }
}

// K3: aggregate-first gather. y_r = rs_r * sum_s rs_s * nodes_s (bf16 hi/lo
// planes), c_r = rs_r * sum_s rs_s (overwrites cnt_recv as float).
// Tail blocks (>= AGGB) do the W1/W2 bf16 hi/lo transpose-split into wt.
__global__ __launch_bounds__(256) void k_agg(
    const float* __restrict__ nodes, const int* __restrict__ off,
    int* __restrict__ cnt_recv, const int* __restrict__ cnt_send,
    const int* __restrict__ srt, ushort* __restrict__ yh,
    ushort* __restrict__ yl, int n, const float* __restrict__ W1,
    const float* __restrict__ W2, ushort* __restrict__ wt) {
  if ((int)blockIdx.x >= AGGB) {  // wsplit: 128 blocks * 256 threads = 32768 ids
    const int id = ((int)blockIdx.x - AGGB) * 256 + threadIdx.x;
    const int mat = id >> 14, idx = id & 16383;
    const int k = idx >> 7, nn = idx & 127;
    const float x = (mat ? W2 : W1)[k * D + nn];
    ushort hi, lo;
    bf16split(x, hi, lo);
    wt[(size_t)mat * 32768 + (size_t)nn * 128 + k] = hi;
    wt[(size_t)mat * 32768 + 16384 + (size_t)nn * 128 + k] = lo;
    return;
  }
  float* cf = (float*)cnt_recv;
  const int hw = threadIdx.x >> 5, ln = threadIdx.x & 31;
  const int ghw = blockIdx.x * 8 + hw;
  const int nhw = AGGB * 8;
  const int c0 = ln * 4;

  for (int r0 = ghw; r0 < n; r0 += 2 * nhw) {
    const int r1 = r0 + nhw;
    const bool has1 = r1 < n;
    const int dg0 = cnt_recv[r0];
    const int o0 = off[r0];
    const int dg1 = has1 ? cnt_recv[r1] : 0;
    const int o1 = has1 ? off[r1] : o0;
    const int safe0 = (dg0 > 0) ? o0 : 0;  // avoid srt[E] garbage index
    const int safe1 = (dg1 > 0) ? o1 : 0;

    int idx0[8], idx1[8];
#pragma unroll
    for (int j = 0; j < 8; ++j) {
      idx0[j] = srt[safe0 + (j < dg0 ? j : 0)];
      idx1[j] = srt[safe1 + (j < dg1 ? j : 0)];
    }
    float4 g0[8], g1[8];
#pragma unroll
    for (int j = 0; j < 8; ++j)
      g0[j] = *(const float4*)(nodes + (size_t)idx0[j] * D + c0);
#pragma unroll
    for (int j = 0; j < 8; ++j)
      g1[j] = *(const float4*)(nodes + (size_t)idx1[j] * D + c0);
    float rs0[8], rs1[8];
#pragma unroll
    for (int j = 0; j < 8; ++j) {
      rs0[j] = (j < dg0) ? rsqrtf(fmaxf((float)cnt_send[idx0[j]], 1.f)) : 0.f;
      rs1[j] = (j < dg1) ? rsqrtf(fmaxf((float)cnt_send[idx1[j]], 1.f)) : 0.f;
    }

    float sx0 = 0.f, sy0 = 0.f, sz0 = 0.f, sw0 = 0.f, cs0 = 0.f;
    float sx1 = 0.f, sy1 = 0.f, sz1 = 0.f, sw1 = 0.f, cs1 = 0.f;
#pragma unroll
    for (int j = 0; j < 8; ++j) {
      sx0 = fmaf(rs0[j], g0[j].x, sx0);
      sy0 = fmaf(rs0[j], g0[j].y, sy0);
      sz0 = fmaf(rs0[j], g0[j].z, sz0);
      sw0 = fmaf(rs0[j], g0[j].w, sw0);
      cs0 += rs0[j];
      sx1 = fmaf(rs1[j], g1[j].x, sx1);
      sy1 = fmaf(rs1[j], g1[j].y, sy1);
      sz1 = fmaf(rs1[j], g1[j].z, sz1);
      sw1 = fmaf(rs1[j], g1[j].w, sw1);
      cs1 += rs1[j];
    }
    for (int i = 8; i < dg0; ++i) {  // rare tail (P(deg>8) ~ 0.19)
      const int s = srt[o0 + i];
      const float r = rsqrtf(fmaxf((float)cnt_send[s], 1.f));
      const float4 c = *(const float4*)(nodes + (size_t)s * D + c0);
      sx0 = fmaf(r, c.x, sx0); sy0 = fmaf(r, c.y, sy0);
      sz0 = fmaf(r, c.z, sz0); sw0 = fmaf(r, c.w, sw0);
      cs0 += r;
    }
    for (int i = 8; i < dg1; ++i) {
      const int s = srt[o1 + i];
      const float r = rsqrtf(fmaxf((float)cnt_send[s], 1.f));
      const float4 c = *(const float4*)(nodes + (size_t)s * D + c0);
      sx1 = fmaf(r, c.x, sx1); sy1 = fmaf(r, c.y, sy1);
      sz1 = fmaf(r, c.z, sz1); sw1 = fmaf(r, c.w, sw1);
      cs1 += r;
    }

    {
      const float rr = rsqrtf(fmaxf((float)dg0, 1.f));
      ushort h0, l0, h1, l1, h2, l2, h3, l3;
      bf16split(sx0 * rr, h0, l0);
      bf16split(sy0 * rr, h1, l1);
      bf16split(sz0 * rr, h2, l2);
      bf16split(sw0 * rr, h3, l3);
      *(ushort4*)(yh + (size_t)r0 * D + c0) = make_ushort4(h0, h1, h2, h3);
      *(ushort4*)(yl + (size_t)r0 * D + c0) = make_ushort4(l0, l1, l2, l3);
      if (ln == 0) cf[r0] = rr * cs0;
    }
    if (has1) {
      const float rr = rsqrtf(fmaxf((float)dg1, 1.f));
      ushort h0, l0, h1, l1, h2, l2, h3, l3;
      bf16split(sx1 * rr, h0, l0);
      bf16split(sy1 * rr, h1, l1);
      bf16split(sz1 * rr, h2, l2);
      bf16split(sw1 * rr, h3, l3);
      *(ushort4*)(yh + (size_t)r1 * D + c0) = make_ushort4(h0, h1, h2, h3);
      *(ushort4*)(yl + (size_t)r1 * D + c0) = make_ushort4(l0, l1, l2, l3);
      if (ln == 0) cf[r1] = rr * cs1;
    }
  }
}

// K4: LDS-free dual-A fused GEMM+epilogue. 64x128 tile, 4 waves, wave w owns
// cols [w*32, w*32+32). All MFMA operands loaded global->VGPR directly in
// fragment layout (per-row 64B clusters, L1/L2-served). nhl (nodes bf16 hi/lo,
// interleaved rows) ALIASES outH: all reads are block-local rows and complete
// before the single __syncthreads(); epilogue then overwrites rows with h.
// h = relu(nodes@W1 + y@W2 + b1 + c*b2 + gvec) + nodes, bf16x3 both GEMMs.
__global__ __launch_bounds__(256, 3) void k_gemm(
    const float* __restrict__ A, const ushort* nhl, const ushort* __restrict__ yh,
    const ushort* __restrict__ yl, const ushort* __restrict__ wt,
    const float* __restrict__ b1, const float* __restrict__ b2,
    const float* __restrict__ gvec, const float* __restrict__ cf,
    float* outH, float* __restrict__ an, int n) {
  const int t = threadIdx.x;
  const int row0 = blockIdx.x * 64;
  const int lane = t & 63, w = t >> 6;
  const int m = lane & 15, quad = lane >> 4;

  floatx4 acc[4][2];
#pragma unroll
  for (int i = 0; i < 4; ++i)
#pragma unroll
    for (int j = 0; j < 2; ++j) acc[i][j] = (floatx4)0.f;

  int rr[4];
#pragma unroll
  for (int i = 0; i < 4; ++i) rr[i] = min(row0 + i * 16 + m, n - 1);

  for (int p = 0; p < 4; ++p) {
    const int kofs = p * 32 + quad * 8;
    short8 a1h[4], a1l[4], a2h[4], a2l[4];
#pragma unroll
    for (int i = 0; i < 4; ++i) {
      const ushort* nb = nhl + (size_t)rr[i] * 256 + kofs;
      a1h[i] = *(const short8*)nb;
      a1l[i] = *(const short8*)(nb + 128);
      const size_t yo = (size_t)rr[i] * D + kofs;
      a2h[i] = *(const short8*)(yh + yo);
      a2l[i] = *(const short8*)(yl + yo);
    }
#pragma unroll
    for (int j = 0; j < 2; ++j) {
      const int col = w * 32 + j * 16 + m;
      const ushort* g1 = wt + (size_t)col * 128 + kofs;
      const short8 w1h = *(const short8*)g1;
      const short8 w1l = *(const short8*)(g1 + 16384);
      const short8 w2h = *(const short8*)(g1 + 32768);
      const short8 w2l = *(const short8*)(g1 + 49152);
#pragma unroll
      for (int i = 0; i < 4; ++i) {
        floatx4 c = acc[i][j];
        c = __builtin_amdgcn_mfma_f32_16x16x32_bf16(a1h[i], w1h, c, 0, 0, 0);
        c = __builtin_amdgcn_mfma_f32_16x16x32_bf16(a1h[i], w1l, c, 0, 0, 0);
        c = __builtin_amdgcn_mfma_f32_16x16x32_bf16(a1l[i], w1h, c, 0, 0, 0);
        c = __builtin_amdgcn_mfma_f32_16x16x32_bf16(a2h[i], w2h, c, 0, 0, 0);
        c = __builtin_amdgcn_mfma_f32_16x16x32_bf16(a2h[i], w2l, c, 0, 0, 0);
        c = __builtin_amdgcn_mfma_f32_16x16x32_bf16(a2l[i], w2h, c, 0, 0, 0);
        acc[i][j] = c;
      }
    }
  }

  __syncthreads();  // all nhl reads done before aliased h writes

  float bb[2], b2c[2];
#pragma unroll
  for (int j = 0; j < 2; ++j) {
    const int col = w * 32 + j * 16 + m;
    bb[j] = b1[col] + gvec[col];
    b2c[j] = b2[col];
  }
  float asum[2] = {0.f, 0.f};
#pragma unroll
  for (int i = 0; i < 4; ++i)
#pragma unroll
    for (int pp = 0; pp < 4; ++pp) {
      const int rg = row0 + i * 16 + quad * 4 + pp;
      if (rg >= n) continue;
      const float crv = cf[rg];
#pragma unroll
      for (int j = 0; j < 2; ++j) {
        const int col = w * 32 + j * 16 + m;
        float v = acc[i][j][pp] + bb[j] + crv * b2c[j];
        v = fmaxf(v, 0.f) + A[(size_t)rg * D + col];
        outH[(size_t)rg * D + col] = v;
        asum[j] += v;
      }
    }
#pragma unroll
  for (int j = 0; j < 2; ++j) {
    float v = asum[j];
    v += __shfl_xor(v, 16);
    v += __shfl_xor(v, 32);
    if (lane < 16) atomicAdd(an + w * 32 + j * 16 + m, v);
  }
}

// K5: g_new = globals + relu(concat([an, globals]) @ Wg + bg), 2-way k-split
__global__ void k_gupdate(const float* __restrict__ an, const float* __restrict__ g,
                          const float* __restrict__ Wg, const float* __restrict__ bg,
                          float* __restrict__ gout) {
  __shared__ float part[256];
  const int j = threadIdx.x & 127, half = threadIdx.x >> 7;
  float acc = 0.f;
  if (half == 0) {
    for (int k = 0; k < D; ++k) acc = fmaf(an[k], Wg[k * D + j], acc);
  } else {
    for (int k = 0; k < D; ++k) acc = fmaf(g[k], Wg[(D + k) * D + j], acc);
  }
  part[threadIdx.x] = acc;
  __syncthreads();
  if (threadIdx.x < D)
    gout[j] = g[j] + fmaxf(bg[j] + part[j] + part[j + 128], 0.f);
}

extern "C" void kernel_launch(void* const* d_in, const int* in_sizes, int n_in,
                              void* d_out, int out_size, void* d_ws, size_t ws_size,
                              hipStream_t stream) {
  const float* nodes = (const float*)d_in[0];
  const float* globals_ = (const float*)d_in[1];
  const int* senders = (const int*)d_in[2];
  const int* receivers = (const int*)d_in[3];
  const float* W1_w = (const float*)d_in[4];
  const float* W1_b = (const float*)d_in[5];
  const float* W2_w = (const float*)d_in[6];
  const float* W2_b = (const float*)d_in[7];
  const float* W3_w = (const float*)d_in[8];
  const float* W3_b = (const float*)d_in[9];
  const float* Wg_w = (const float*)d_in[10];
  const float* Wg_b = (const float*)d_in[11];
  const int N = in_sizes[0] / D;
  const int E = in_sizes[2];
  const int nb = (N + SCH - 1) / SCH;  // <= 256
  const int nbE = (E + 255) / 256;
  const int nsb = (N * 16 + 255) / 256;  // node-split blocks

  float* h = (float*)d_out;
  float* gout = h + (size_t)N * D;
  ushort* nhl = (ushort*)d_out;  // nodes bf16 hi/lo, interleaved rows, = h region

  float* ws = (float*)d_ws;
  ushort* yh = (ushort*)ws;                    // N*128 ushorts
  ushort* yl = yh + (size_t)N * D;             // N*128 ushorts
  int* cnt_send = (int*)(yl + (size_t)N * D);  // N   (zeroed)
  int* cnt_recv = cnt_send + N;                // N   (zeroed; becomes c_r float)
  int* bsum = cnt_recv + N;                    // 256 (zeroed; scan publish slots)
  float* an = (float*)(bsum + 256);            // D   (zeroed)
  int* off = (int*)(an + D);                   // N
  int* cursor = off + N;                       // N (dead after k_fill -> wt)
  int* srt = cursor + N;                       // E
  float* gvec = (float*)(srt + E);             // D
  ushort* wt = (ushort*)cursor;                // 256 KB, reused after k_fill

  (void)hipMemsetAsync(cnt_send, 0, (size_t)(2 * N + 256 + D) * sizeof(int), stream);

  hipLaunchKernelGGL(k_front, dim3(nbE + 1 + nsb), dim3(256), 0, stream,
                     senders, receivers, cnt_send, cnt_recv, E, nbE,
                     globals_, W3_w, W3_b, gvec, nodes, nhl, N);
  hipLaunchKernelGGL(k_scan, dim3(nb), dim3(256), 0, stream,
                     cnt_recv, bsum, off, cursor, N);
  hipLaunchKernelGGL(k_fill, dim3(nbE), dim3(256), 0, stream,
                     senders, receivers, cursor, srt, E);
  hipLaunchKernelGGL(k_agg, dim3(AGGB + 128), dim3(256), 0, stream,
                     nodes, off, cnt_recv, cnt_send, srt, yh, yl, N,
                     W1_w, W2_w, wt);
  hipLaunchKernelGGL(k_gemm, dim3((N + 63) / 64), dim3(256), 0, stream,
                     nodes, nhl, yh, yl, wt, W1_b, W2_b, gvec,
                     (const float*)cnt_recv, h, an, N);
  hipLaunchKernelGGL(k_gupdate, dim3(1), dim3(256), 0, stream, an, globals_,
                     Wg_w, Wg_b, gout);
}

// Round 3
// 376.041 us; speedup vs baseline: 1.0748x; 1.0748x over previous
//
#include <hip/hip_runtime.h>

#define D 128
#define SCH 1024
#define AGGB 2048  // gather blocks (wsplit rides as 128 extra tail blocks)

typedef __attribute__((ext_vector_type(8))) short short8;
typedef __attribute__((ext_vector_type(4))) float floatx4;

// RNE split of fp32 into bf16 hi + bf16 lo (x ~= hi + lo, err ~2^-17 |x|)
__device__ inline void bf16split(float x, ushort& hi, ushort& lo) {
  unsigned u = __float_as_uint(x);
  unsigned rh = (u + 0x7FFFu + ((u >> 16) & 1u)) & 0xFFFF0000u;
  hi = (ushort)(rh >> 16);
  float fl = x - __uint_as_float(rh);
  unsigned ul = __float_as_uint(fl);
  lo = (ushort)((ul + 0x7FFFu + ((ul >> 16) & 1u)) >> 16);
}

// K0: fused front. blocks [0,nbE): degree histograms; block nbE: gvec = g@W3+b3;
// blocks (nbE, nbE+nsb]: split nodes fp32 -> interleaved bf16 hi/lo rows in
// nhl (= d_out h region, row r: ushorts [r*256, r*256+128)=hi, +128=lo).
__global__ void k_front(const int* __restrict__ snd, const int* __restrict__ rcv,
                        int* __restrict__ cs, int* __restrict__ cr, int E, int nbE,
                        const float* __restrict__ g, const float* __restrict__ W3,
                        const float* __restrict__ b3, float* __restrict__ gvec,
                        const float* __restrict__ nodes, ushort* __restrict__ nhl,
                        int n) {
  __shared__ float part[256];
  const int b = blockIdx.x;
  if (b < nbE) {
    const int e = b * 256 + threadIdx.x;
    if (e < E) {
      atomicAdd(cs + snd[e], 1);
      atomicAdd(cr + rcv[e], 1);
    }
    return;
  }
  if (b == nbE) {
    const int j = threadIdx.x & 127, half = threadIdx.x >> 7;
    float acc = 0.f;
    for (int k = half * 64; k < half * 64 + 64; ++k)
      acc = fmaf(g[k], W3[k * D + j], acc);
    part[threadIdx.x] = acc;
    __syncthreads();
    if (threadIdx.x < D) gvec[j] = b3[j] + part[j] + part[j + 128];
    return;
  }
  // nodes split: 16 threads/row, 8 floats/thread
  const int id = (b - nbE - 1) * 256 + threadIdx.x;
  if (id >= n * 16) return;
  const int r = id >> 4, c = (id & 15) * 8;
  const float* gp = nodes + (size_t)r * D + c;
  const float4 v0 = *(const float4*)gp;
  const float4 v1 = *(const float4*)(gp + 4);
  ushort h0, l0, h1, l1, h2, l2, h3, l3;
  ushort* ob = nhl + (size_t)r * 256;
  bf16split(v0.x, h0, l0); bf16split(v0.y, h1, l1);
  bf16split(v0.z, h2, l2); bf16split(v0.w, h3, l3);
  *(ushort4*)(ob + c) = make_ushort4(h0, h1, h2, h3);
  *(ushort4*)(ob + 128 + c) = make_ushort4(l0, l1, l2, l3);
  bf16split(v1.x, h0, l0); bf16split(v1.y, h1, l1);
  bf16split(v1.z, h2, l2); bf16split(v1.w, h3, l3);
  *(ushort4*)(ob + c + 4) = make_ushort4(h0, h1, h2, h3);
  *(ushort4*)(ob + 128 + c + 4) = make_ushort4(l0, l1, l2, l3);
}

// K1: single-pass exclusive scan of cnt -> off, cursor (lookback via atomics).
__global__ void k_scan(const int* __restrict__ cnt, int* __restrict__ bsum,
                       int* __restrict__ off, int* __restrict__ cursor, int n) {
  __shared__ int sh[256];
  __shared__ int red[4];
  const int t = threadIdx.x, b = blockIdx.x;
  const int base = b * SCH + t * 4;
  int4 v = make_int4(0, 0, 0, 0);
  if (base < n) v = *(const int4*)(cnt + base);
  const int s = v.x + v.y + v.z + v.w;
  sh[t] = s;
  __syncthreads();
  for (int st = 1; st < 256; st <<= 1) {
    const int u = (t >= st) ? sh[t - st] : 0;
    __syncthreads();
    sh[t] += u;
    __syncthreads();
  }
  if (t == 255) atomicExch(bsum + b, sh[255] + 1);  // publish (never 0)
  int pre = 0;
  if (t < b) {
    int x = atomicAdd(bsum + t, 0);
    while (x == 0) {
      __builtin_amdgcn_s_sleep(1);
      x = atomicAdd(bsum + t, 0);
    }
    pre = x - 1;
  }
#pragma unroll
  for (int o = 32; o > 0; o >>= 1) pre += __shfl_down(pre, o, 64);
  if ((t & 63) == 0) red[t >> 6] = pre;
  __syncthreads();
  const int gbase = red[0] + red[1] + red[2] + red[3];
  const int ex = sh[t] - s + gbase;
  if (base < n) {
    const int4 o4 = make_int4(ex, ex + v.x, ex + v.x + v.y, ex + v.x + v.y + v.z);
    *(int4*)(off + base) = o4;
    *(int4*)(cursor + base) = o4;
  }
}

// K2: CSR fill (bucket edges by receiver)
__global__ void k_fill(const int* __restrict__ snd, const int* __restrict__ rcv,
                       int* __restrict__ cursor, int* __restrict__ srt, int E) {
  const int e = blockIdx.x * blockDim.x + threadIdx.x;
  if (e < E) {
    const int p = atomicAdd(cursor + rcv[e], 1);
    srt[p] = snd[e];
  }
}

// K3: aggregate-first gather. y_r = rs_r * sum_s rs_s * nodes_s (bf16 hi/lo
// planes), c_r = rs_r * sum_s rs_s (overwrites cnt_recv as float).
// Tail blocks (>= AGGB) do the W1/W2 bf16 hi/lo transpose-split into wt.
__global__ __launch_bounds__(256) void k_agg(
    const float* __restrict__ nodes, const int* __restrict__ off,
    int* __restrict__ cnt_recv, const int* __restrict__ cnt_send,
    const int* __restrict__ srt, ushort* __restrict__ yh,
    ushort* __restrict__ yl, int n, const float* __restrict__ W1,
    const float* __restrict__ W2, ushort* __restrict__ wt) {
  if ((int)blockIdx.x >= AGGB) {  // wsplit: 128 blocks * 256 threads = 32768 ids
    const int id = ((int)blockIdx.x - AGGB) * 256 + threadIdx.x;
    const int mat = id >> 14, idx = id & 16383;
    const int k = idx >> 7, nn = idx & 127;
    const float x = (mat ? W2 : W1)[k * D + nn];
    ushort hi, lo;
    bf16split(x, hi, lo);
    wt[(size_t)mat * 32768 + (size_t)nn * 128 + k] = hi;
    wt[(size_t)mat * 32768 + 16384 + (size_t)nn * 128 + k] = lo;
    return;
  }
  float* cf = (float*)cnt_recv;
  const int hw = threadIdx.x >> 5, ln = threadIdx.x & 31;
  const int ghw = blockIdx.x * 8 + hw;
  const int nhw = AGGB * 8;
  const int c0 = ln * 4;

  for (int r0 = ghw; r0 < n; r0 += 2 * nhw) {
    const int r1 = r0 + nhw;
    const bool has1 = r1 < n;
    const int dg0 = cnt_recv[r0];
    const int o0 = off[r0];
    const int dg1 = has1 ? cnt_recv[r1] : 0;
    const int o1 = has1 ? off[r1] : o0;
    const int safe0 = (dg0 > 0) ? o0 : 0;  // avoid srt[E] garbage index
    const int safe1 = (dg1 > 0) ? o1 : 0;

    int idx0[8], idx1[8];
#pragma unroll
    for (int j = 0; j < 8; ++j) {
      idx0[j] = srt[safe0 + (j < dg0 ? j : 0)];
      idx1[j] = srt[safe1 + (j < dg1 ? j : 0)];
    }
    float4 g0[8], g1[8];
#pragma unroll
    for (int j = 0; j < 8; ++j)
      g0[j] = *(const float4*)(nodes + (size_t)idx0[j] * D + c0);
#pragma unroll
    for (int j = 0; j < 8; ++j)
      g1[j] = *(const float4*)(nodes + (size_t)idx1[j] * D + c0);
    float rs0[8], rs1[8];
#pragma unroll
    for (int j = 0; j < 8; ++j) {
      rs0[j] = (j < dg0) ? rsqrtf(fmaxf((float)cnt_send[idx0[j]], 1.f)) : 0.f;
      rs1[j] = (j < dg1) ? rsqrtf(fmaxf((float)cnt_send[idx1[j]], 1.f)) : 0.f;
    }

    float sx0 = 0.f, sy0 = 0.f, sz0 = 0.f, sw0 = 0.f, cs0 = 0.f;
    float sx1 = 0.f, sy1 = 0.f, sz1 = 0.f, sw1 = 0.f, cs1 = 0.f;
#pragma unroll
    for (int j = 0; j < 8; ++j) {
      sx0 = fmaf(rs0[j], g0[j].x, sx0);
      sy0 = fmaf(rs0[j], g0[j].y, sy0);
      sz0 = fmaf(rs0[j], g0[j].z, sz0);
      sw0 = fmaf(rs0[j], g0[j].w, sw0);
      cs0 += rs0[j];
      sx1 = fmaf(rs1[j], g1[j].x, sx1);
      sy1 = fmaf(rs1[j], g1[j].y, sy1);
      sz1 = fmaf(rs1[j], g1[j].z, sz1);
      sw1 = fmaf(rs1[j], g1[j].w, sw1);
      cs1 += rs1[j];
    }
    for (int i = 8; i < dg0; ++i) {  // rare tail (P(deg>8) ~ 0.19)
      const int s = srt[o0 + i];
      const float r = rsqrtf(fmaxf((float)cnt_send[s], 1.f));
      const float4 c = *(const float4*)(nodes + (size_t)s * D + c0);
      sx0 = fmaf(r, c.x, sx0); sy0 = fmaf(r, c.y, sy0);
      sz0 = fmaf(r, c.z, sz0); sw0 = fmaf(r, c.w, sw0);
      cs0 += r;
    }
    for (int i = 8; i < dg1; ++i) {
      const int s = srt[o1 + i];
      const float r = rsqrtf(fmaxf((float)cnt_send[s], 1.f));
      const float4 c = *(const float4*)(nodes + (size_t)s * D + c0);
      sx1 = fmaf(r, c.x, sx1); sy1 = fmaf(r, c.y, sy1);
      sz1 = fmaf(r, c.z, sz1); sw1 = fmaf(r, c.w, sw1);
      cs1 += r;
    }

    {
      const float rr = rsqrtf(fmaxf((float)dg0, 1.f));
      ushort h0, l0, h1, l1, h2, l2, h3, l3;
      bf16split(sx0 * rr, h0, l0);
      bf16split(sy0 * rr, h1, l1);
      bf16split(sz0 * rr, h2, l2);
      bf16split(sw0 * rr, h3, l3);
      *(ushort4*)(yh + (size_t)r0 * D + c0) = make_ushort4(h0, h1, h2, h3);
      *(ushort4*)(yl + (size_t)r0 * D + c0) = make_ushort4(l0, l1, l2, l3);
      if (ln == 0) cf[r0] = rr * cs0;
    }
    if (has1) {
      const float rr = rsqrtf(fmaxf((float)dg1, 1.f));
      ushort h0, l0, h1, l1, h2, l2, h3, l3;
      bf16split(sx1 * rr, h0, l0);
      bf16split(sy1 * rr, h1, l1);
      bf16split(sz1 * rr, h2, l2);
      bf16split(sw1 * rr, h3, l3);
      *(ushort4*)(yh + (size_t)r1 * D + c0) = make_ushort4(h0, h1, h2, h3);
      *(ushort4*)(yl + (size_t)r1 * D + c0) = make_ushort4(l0, l1, l2, l3);
      if (ln == 0) cf[r1] = rr * cs1;
    }
  }
}

// K4: dual-A fused GEMM+epilogue, pipelined. 64x128 tile, 4 waves, wave w owns
// cols [w*32, w*32+32). A planes (n_hi,n_lo,y_hi,y_lo) staged via LDS as pure
// uint4 copies (pre-split upstream), DOUBLE-BUFFERED with depth-2 register
// prefetch: one barrier per pass, global loads for pass p+2 issue before the
// MFMAs of pass p. W frags load direct global->reg (wt is L1/L2-resident).
// nhl ALIASES outH (block-local rows; reads complete before epilogue writes).
// h = relu(nodes@W1 + y@W2 + b1 + c*b2 + gvec) + nodes, bf16x3 both GEMMs.
__global__ __launch_bounds__(256, 4) void k_gemm(
    const float* __restrict__ A, const ushort* nhl, const ushort* __restrict__ yh,
    const ushort* __restrict__ yl, const ushort* __restrict__ wt,
    const float* __restrict__ b1, const float* __restrict__ b2,
    const float* __restrict__ gvec, const float* __restrict__ cf,
    float* outH, float* __restrict__ an, int n) {
  __shared__ ushort As[2][4][64 * 40];  // [buf][plane][row*40+k], 40 KB
  const int t = threadIdx.x;
  const int row0 = blockIdx.x * 64;
  const int lane = t & 63, w = t >> 6;
  const int m = lane & 15, quad = lane >> 4;

  floatx4 acc[4][2];
#pragma unroll
  for (int i = 0; i < 4; ++i)
#pragma unroll
    for (int j = 0; j < 2; ++j) acc[i][j] = (floatx4)0.f;

  // staging coords: 4 threads/row, 16B (8 ushorts) each
  const int srow = t >> 2, ko = (t & 3) * 8;
  const int grow = min(row0 + srow, n - 1);
  const ushort* nb = nhl + (size_t)grow * 256 + ko;
  const ushort* yhb = yh + (size_t)grow * D + ko;
  const ushort* ylb = yl + (size_t)grow * D + ko;
  const int sa = srow * 40 + ko;

  uint4 r0, r1, r2, r3;
#define LOADP(p)                                   \
  {                                                \
    r0 = *(const uint4*)(nb + (p) * 32);           \
    r1 = *(const uint4*)(nb + 128 + (p) * 32);     \
    r2 = *(const uint4*)(yhb + (p) * 32);          \
    r3 = *(const uint4*)(ylb + (p) * 32);          \
  }
#define STOREB(buf)                                \
  {                                                \
    *(uint4*)&As[buf][0][sa] = r0;                 \
    *(uint4*)&As[buf][1][sa] = r1;                 \
    *(uint4*)&As[buf][2][sa] = r2;                 \
    *(uint4*)&As[buf][3][sa] = r3;                 \
  }

  LOADP(0);
  STOREB(0);
  LOADP(1);
  __syncthreads();

  for (int p = 0; p < 4; ++p) {
    if (p < 3) STOREB((p + 1) & 1);  // regs loaded a pass ago; buf^1 free since
    if (p < 2) LOADP(p + 2);         // last barrier. prefetch p+2 under MFMAs.
    const ushort* Ab = &As[p & 1][0][0];
#pragma unroll
    for (int j = 0; j < 2; ++j) {
      const ushort* g1 = wt + (size_t)(w * 32 + j * 16 + m) * 128 + p * 32 + quad * 8;
      const short8 w1h = *(const short8*)g1;
      const short8 w1l = *(const short8*)(g1 + 16384);
      const short8 w2h = *(const short8*)(g1 + 32768);
      const short8 w2l = *(const short8*)(g1 + 49152);
#pragma unroll
      for (int i = 0; i < 4; ++i) {
        const int r = (i * 16 + m) * 40 + quad * 8;
        const short8 a1h = *(const short8*)&Ab[r];
        const short8 a1l = *(const short8*)&Ab[2560 + r];
        const short8 a2h = *(const short8*)&Ab[5120 + r];
        const short8 a2l = *(const short8*)&Ab[7680 + r];
        floatx4 c = acc[i][j];
        c = __builtin_amdgcn_mfma_f32_16x16x32_bf16(a1h, w1h, c, 0, 0, 0);
        c = __builtin_amdgcn_mfma_f32_16x16x32_bf16(a1h, w1l, c, 0, 0, 0);
        c = __builtin_amdgcn_mfma_f32_16x16x32_bf16(a1l, w1h, c, 0, 0, 0);
        c = __builtin_amdgcn_mfma_f32_16x16x32_bf16(a2h, w2h, c, 0, 0, 0);
        c = __builtin_amdgcn_mfma_f32_16x16x32_bf16(a2h, w2l, c, 0, 0, 0);
        c = __builtin_amdgcn_mfma_f32_16x16x32_bf16(a2l, w2h, c, 0, 0, 0);
        acc[i][j] = c;
      }
    }
    __syncthreads();
  }
#undef LOADP
#undef STOREB

  // --- epilogue: C/D layout col=lane&15, row=quad*4+reg ---
  float bb[2], b2c[2];
#pragma unroll
  for (int j = 0; j < 2; ++j) {
    const int col = w * 32 + j * 16 + m;
    bb[j] = b1[col] + gvec[col];
    b2c[j] = b2[col];
  }
  float asum[2] = {0.f, 0.f};
#pragma unroll
  for (int i = 0; i < 4; ++i)
#pragma unroll
    for (int pp = 0; pp < 4; ++pp) {
      const int rg = row0 + i * 16 + quad * 4 + pp;
      if (rg >= n) continue;
      const float crv = cf[rg];
#pragma unroll
      for (int j = 0; j < 2; ++j) {
        const int col = w * 32 + j * 16 + m;
        float v = acc[i][j][pp] + bb[j] + crv * b2c[j];
        v = fmaxf(v, 0.f) + A[(size_t)rg * D + col];
        outH[(size_t)rg * D + col] = v;
        asum[j] += v;
      }
    }
#pragma unroll
  for (int j = 0; j < 2; ++j) {
    float v = asum[j];
    v += __shfl_xor(v, 16);
    v += __shfl_xor(v, 32);
    if (lane < 16) atomicAdd(an + w * 32 + j * 16 + m, v);
  }
}

// K5: g_new = globals + relu(concat([an, globals]) @ Wg + bg), 2-way k-split
__global__ void k_gupdate(const float* __restrict__ an, const float* __restrict__ g,
                          const float* __restrict__ Wg, const float* __restrict__ bg,
                          float* __restrict__ gout) {
  __shared__ float part[256];
  const int j = threadIdx.x & 127, half = threadIdx.x >> 7;
  float acc = 0.f;
  if (half == 0) {
    for (int k = 0; k < D; ++k) acc = fmaf(an[k], Wg[k * D + j], acc);
  } else {
    for (int k = 0; k < D; ++k) acc = fmaf(g[k], Wg[(D + k) * D + j], acc);
  }
  part[threadIdx.x] = acc;
  __syncthreads();
  if (threadIdx.x < D)
    gout[j] = g[j] + fmaxf(bg[j] + part[j] + part[j + 128], 0.f);
}

extern "C" void kernel_launch(void* const* d_in, const int* in_sizes, int n_in,
                              void* d_out, int out_size, void* d_ws, size_t ws_size,
                              hipStream_t stream) {
  const float* nodes = (const float*)d_in[0];
  const float* globals_ = (const float*)d_in[1];
  const int* senders = (const int*)d_in[2];
  const int* receivers = (const int*)d_in[3];
  const float* W1_w = (const float*)d_in[4];
  const float* W1_b = (const float*)d_in[5];
  const float* W2_w = (const float*)d_in[6];
  const float* W2_b = (const float*)d_in[7];
  const float* W3_w = (const float*)d_in[8];
  const float* W3_b = (const float*)d_in[9];
  const float* Wg_w = (const float*)d_in[10];
  const float* Wg_b = (const float*)d_in[11];
  const int N = in_sizes[0] / D;
  const int E = in_sizes[2];
  const int nb = (N + SCH - 1) / SCH;  // <= 256
  const int nbE = (E + 255) / 256;
  const int nsb = (N * 16 + 255) / 256;  // node-split blocks

  float* h = (float*)d_out;
  float* gout = h + (size_t)N * D;
  ushort* nhl = (ushort*)d_out;  // nodes bf16 hi/lo, interleaved rows, = h region

  float* ws = (float*)d_ws;
  ushort* yh = (ushort*)ws;                    // N*128 ushorts
  ushort* yl = yh + (size_t)N * D;             // N*128 ushorts
  int* cnt_send = (int*)(yl + (size_t)N * D);  // N   (zeroed)
  int* cnt_recv = cnt_send + N;                // N   (zeroed; becomes c_r float)
  int* bsum = cnt_recv + N;                    // 256 (zeroed; scan publish slots)
  float* an = (float*)(bsum + 256);            // D   (zeroed)
  int* off = (int*)(an + D);                   // N
  int* cursor = off + N;                       // N (dead after k_fill -> wt)
  int* srt = cursor + N;                       // E
  float* gvec = (float*)(srt + E);             // D
  ushort* wt = (ushort*)cursor;                // 128 KB, reused after k_fill

  (void)hipMemsetAsync(cnt_send, 0, (size_t)(2 * N + 256 + D) * sizeof(int), stream);

  hipLaunchKernelGGL(k_front, dim3(nbE + 1 + nsb), dim3(256), 0, stream,
                     senders, receivers, cnt_send, cnt_recv, E, nbE,
                     globals_, W3_w, W3_b, gvec, nodes, nhl, N);
  hipLaunchKernelGGL(k_scan, dim3(nb), dim3(256), 0, stream,
                     cnt_recv, bsum, off, cursor, N);
  hipLaunchKernelGGL(k_fill, dim3(nbE), dim3(256), 0, stream,
                     senders, receivers, cursor, srt, E);
  hipLaunchKernelGGL(k_agg, dim3(AGGB + 128), dim3(256), 0, stream,
                     nodes, off, cnt_recv, cnt_send, srt, yh, yl, N,
                     W1_w, W2_w, wt);
  hipLaunchKernelGGL(k_gemm, dim3((N + 63) / 64), dim3(256), 0, stream,
                     nodes, nhl, yh, yl, wt, W1_b, W2_b, gvec,
                     (const float*)cnt_recv, h, an, N);
  hipLaunchKernelGGL(k_gupdate, dim3(1), dim3(256), 0, stream, an, globals_,
                     Wg_w, Wg_b, gout);
}

// Round 4
// 350.171 us; speedup vs baseline: 1.1542x; 1.0739x over previous
//
#include <hip/hip_runtime.h>

#define D 128
#define AGGB 2048    // gather blocks
#define MAXDEG 16    // direct CSR slots per receiver (P(deg>16|Poi(6.4)) ~ 3e-4)
#define OVFCAP 16384 // overflow pair capacity

typedef __attribute__((ext_vector_type(8))) short short8;
typedef __attribute__((ext_vector_type(4))) float floatx4;

// RNE split of fp32 into bf16 hi + bf16 lo (x ~= hi + lo, err ~2^-17 |x|)
__device__ inline void bf16split(float x, ushort& hi, ushort& lo) {
  unsigned u = __float_as_uint(x);
  unsigned rh = (u + 0x7FFFu + ((u >> 16) & 1u)) & 0xFFFF0000u;
  hi = (ushort)(rh >> 16);
  float fl = x - __uint_as_float(rh);
  unsigned ul = __float_as_uint(fl);
  lo = (ushort)((ul + 0x7FFFu + ((ul >> 16) & 1u)) >> 16);
}

// K0: fused front.
// blocks [0,nbE): per edge: send-degree atomic + recv atomic that ALSO places
//   the edge into the direct CSR bucket srtp[r*16+p] (overflow -> ovf list).
// block nbE: gvec = g@W3 + b3.
// blocks [nbE+1, nbE+129): W1/W2 bf16 hi/lo transpose-split into wt.
__global__ void k_front(const int* __restrict__ snd, const int* __restrict__ rcv,
                        int* __restrict__ cs, int* __restrict__ cr,
                        int* __restrict__ srtp, int* __restrict__ ovf,
                        int* __restrict__ ovfn, int E, int nbE,
                        const float* __restrict__ g, const float* __restrict__ W3,
                        const float* __restrict__ b3, float* __restrict__ gvec,
                        const float* __restrict__ W1, const float* __restrict__ W2,
                        ushort* __restrict__ wt) {
  __shared__ float part[256];
  const int b = blockIdx.x;
  if (b < nbE) {
    const int e = b * 256 + threadIdx.x;
    if (e < E) {
      const int s = snd[e], r = rcv[e];
      atomicAdd(cs + s, 1);
      const int p = atomicAdd(cr + r, 1);
      if (p < MAXDEG) {
        srtp[r * MAXDEG + p] = s;
      } else {
        const int q = atomicAdd(ovfn, 1);
        if (q < OVFCAP) {
          ovf[2 * q] = r;
          ovf[2 * q + 1] = s;
        }
      }
    }
    return;
  }
  if (b == nbE) {
    const int j = threadIdx.x & 127, half = threadIdx.x >> 7;
    float acc = 0.f;
    for (int k = half * 64; k < half * 64 + 64; ++k)
      acc = fmaf(g[k], W3[k * D + j], acc);
    part[threadIdx.x] = acc;
    __syncthreads();
    if (threadIdx.x < D) gvec[j] = b3[j] + part[j] + part[j + 128];
    return;
  }
  // wsplit: 128 blocks * 256 threads = 32768 ids
  const int id = (b - nbE - 1) * 256 + threadIdx.x;
  const int mat = id >> 14, idx = id & 16383;
  const int k = idx >> 7, nn = idx & 127;
  const float x = (mat ? W2 : W1)[k * D + nn];
  ushort hi, lo;
  bf16split(x, hi, lo);
  wt[(size_t)mat * 32768 + (size_t)nn * 128 + k] = hi;
  wt[(size_t)mat * 32768 + 16384 + (size_t)nn * 128 + k] = lo;
}

// K1: aggregate-first gather via direct CSR. y_r = rs_r * sum_s rs_s*nodes_s
// (bf16 hi/lo planes), c_r = rs_r * sum_s rs_s (overwrites cnt_recv as float).
// Half-wave per row, float4/lane, two rows in flight. Unwritten srtp slots may
// hold garbage -> select idx to 0 when j>=dg (load itself is in-bounds).
// Rows with dg > MAXDEG scan the tiny overflow list.
__global__ __launch_bounds__(256) void k_agg(
    const float* __restrict__ nodes, int* __restrict__ cnt_recv,
    const int* __restrict__ cnt_send, const int* __restrict__ srtp,
    const int* __restrict__ ovf, const int* __restrict__ ovfn,
    ushort* __restrict__ yh, ushort* __restrict__ yl, int n) {
  float* cf = (float*)cnt_recv;
  const int hw = threadIdx.x >> 5, ln = threadIdx.x & 31;
  const int ghw = blockIdx.x * 8 + hw;
  const int nhw = AGGB * 8;
  const int c0 = ln * 4;

  for (int r0 = ghw; r0 < n; r0 += 2 * nhw) {
    const int r1 = r0 + nhw;
    const bool has1 = r1 < n;
    const int dg0 = cnt_recv[r0];
    const int dg1 = has1 ? cnt_recv[r1] : 0;
    const int base0 = r0 * MAXDEG;
    const int base1 = (has1 ? r1 : 0) * MAXDEG;

    int idx0[8], idx1[8];
#pragma unroll
    for (int j = 0; j < 8; ++j) {
      const int raw0 = srtp[base0 + j];
      const int raw1 = srtp[base1 + j];
      idx0[j] = (j < dg0) ? raw0 : 0;
      idx1[j] = (j < dg1) ? raw1 : 0;
    }
    float4 g0[8], g1[8];
#pragma unroll
    for (int j = 0; j < 8; ++j)
      g0[j] = *(const float4*)(nodes + (size_t)idx0[j] * D + c0);
#pragma unroll
    for (int j = 0; j < 8; ++j)
      g1[j] = *(const float4*)(nodes + (size_t)idx1[j] * D + c0);
    float rs0[8], rs1[8];
#pragma unroll
    for (int j = 0; j < 8; ++j) {
      rs0[j] = (j < dg0) ? rsqrtf(fmaxf((float)cnt_send[idx0[j]], 1.f)) : 0.f;
      rs1[j] = (j < dg1) ? rsqrtf(fmaxf((float)cnt_send[idx1[j]], 1.f)) : 0.f;
    }

    float sx0 = 0.f, sy0 = 0.f, sz0 = 0.f, sw0 = 0.f, cs0 = 0.f;
    float sx1 = 0.f, sy1 = 0.f, sz1 = 0.f, sw1 = 0.f, cs1 = 0.f;
#pragma unroll
    for (int j = 0; j < 8; ++j) {
      sx0 = fmaf(rs0[j], g0[j].x, sx0);
      sy0 = fmaf(rs0[j], g0[j].y, sy0);
      sz0 = fmaf(rs0[j], g0[j].z, sz0);
      sw0 = fmaf(rs0[j], g0[j].w, sw0);
      cs0 += rs0[j];
      sx1 = fmaf(rs1[j], g1[j].x, sx1);
      sy1 = fmaf(rs1[j], g1[j].y, sy1);
      sz1 = fmaf(rs1[j], g1[j].z, sz1);
      sw1 = fmaf(rs1[j], g1[j].w, sw1);
      cs1 += rs1[j];
    }
    for (int i = 8; i < min(dg0, MAXDEG); ++i) {
      const int s = srtp[base0 + i];
      const float r = rsqrtf(fmaxf((float)cnt_send[s], 1.f));
      const float4 c = *(const float4*)(nodes + (size_t)s * D + c0);
      sx0 = fmaf(r, c.x, sx0); sy0 = fmaf(r, c.y, sy0);
      sz0 = fmaf(r, c.z, sz0); sw0 = fmaf(r, c.w, sw0);
      cs0 += r;
    }
    for (int i = 8; i < min(dg1, MAXDEG); ++i) {
      const int s = srtp[base1 + i];
      const float r = rsqrtf(fmaxf((float)cnt_send[s], 1.f));
      const float4 c = *(const float4*)(nodes + (size_t)s * D + c0);
      sx1 = fmaf(r, c.x, sx1); sy1 = fmaf(r, c.y, sy1);
      sz1 = fmaf(r, c.z, sz1); sw1 = fmaf(r, c.w, sw1);
      cs1 += r;
    }
    if (dg0 > MAXDEG) {  // rare overflow rows (~3e-4 of rows)
      const int novf = min(*ovfn, OVFCAP);
      for (int k2 = 0; k2 < novf; ++k2) {
        if (ovf[2 * k2] == r0) {
          const int s = ovf[2 * k2 + 1];
          const float r = rsqrtf(fmaxf((float)cnt_send[s], 1.f));
          const float4 c = *(const float4*)(nodes + (size_t)s * D + c0);
          sx0 = fmaf(r, c.x, sx0); sy0 = fmaf(r, c.y, sy0);
          sz0 = fmaf(r, c.z, sz0); sw0 = fmaf(r, c.w, sw0);
          cs0 += r;
        }
      }
    }
    if (dg1 > MAXDEG) {
      const int novf = min(*ovfn, OVFCAP);
      for (int k2 = 0; k2 < novf; ++k2) {
        if (ovf[2 * k2] == r1) {
          const int s = ovf[2 * k2 + 1];
          const float r = rsqrtf(fmaxf((float)cnt_send[s], 1.f));
          const float4 c = *(const float4*)(nodes + (size_t)s * D + c0);
          sx1 = fmaf(r, c.x, sx1); sy1 = fmaf(r, c.y, sy1);
          sz1 = fmaf(r, c.z, sz1); sw1 = fmaf(r, c.w, sw1);
          cs1 += r;
        }
      }
    }

    {
      const float rr = rsqrtf(fmaxf((float)dg0, 1.f));
      ushort h0, l0, h1, l1, h2, l2, h3, l3;
      bf16split(sx0 * rr, h0, l0);
      bf16split(sy0 * rr, h1, l1);
      bf16split(sz0 * rr, h2, l2);
      bf16split(sw0 * rr, h3, l3);
      *(ushort4*)(yh + (size_t)r0 * D + c0) = make_ushort4(h0, h1, h2, h3);
      *(ushort4*)(yl + (size_t)r0 * D + c0) = make_ushort4(l0, l1, l2, l3);
      if (ln == 0) cf[r0] = rr * cs0;
    }
    if (has1) {
      const float rr = rsqrtf(fmaxf((float)dg1, 1.f));
      ushort h0, l0, h1, l1, h2, l2, h3, l3;
      bf16split(sx1 * rr, h0, l0);
      bf16split(sy1 * rr, h1, l1);
      bf16split(sz1 * rr, h2, l2);
      bf16split(sw1 * rr, h3, l3);
      *(ushort4*)(yh + (size_t)r1 * D + c0) = make_ushort4(h0, h1, h2, h3);
      *(ushort4*)(yl + (size_t)r1 * D + c0) = make_ushort4(l0, l1, l2, l3);
      if (ln == 0) cf[r1] = rr * cs1;
    }
  }
}

// K2: dual-A fused GEMM+epilogue, pipelined, split-at-stage. 64x128 tile,
// 4 waves, wave w owns cols [w*32, w*32+32). A1 staged from fp32 nodes with
// bf16split at ds_write time; A2 = pre-split y planes (uint4 copy). Double-
// buffered LDS (40 KB), depth-2 register prefetch, ONE barrier per pass.
// W frags direct global->reg (wt L1/L2-resident). Epilogue residual re-reads
// A (L1/L2-warm from the K-loop).
// h = relu(nodes@W1 + y@W2 + b1 + c*b2 + gvec) + nodes, bf16x3 both GEMMs.
__global__ __launch_bounds__(256, 4) void k_gemm(
    const float* __restrict__ A, const ushort* __restrict__ yh,
    const ushort* __restrict__ yl, const ushort* __restrict__ wt,
    const float* __restrict__ b1, const float* __restrict__ b2,
    const float* __restrict__ gvec, const float* __restrict__ cf,
    float* __restrict__ outH, float* __restrict__ an, int n) {
  __shared__ ushort As[2 * 4 * 2560];  // [buf][plane: n_hi,n_lo,y_hi,y_lo][64*40]
  const int t = threadIdx.x;
  const int row0 = blockIdx.x * 64;
  const int lane = t & 63, w = t >> 6;
  const int m = lane & 15, quad = lane >> 4;

  floatx4 acc[4][2];
#pragma unroll
  for (int i = 0; i < 4; ++i)
#pragma unroll
    for (int j = 0; j < 2; ++j) acc[i][j] = (floatx4)0.f;

  // staging coords: 4 threads/row, 8 elems (32B fp32 / 16B plane) each
  const int srow = t >> 2, ko = (t & 3) * 8;
  const int grow = min(row0 + srow, n - 1);
  const float* Ag = A + (size_t)grow * D + ko;
  const ushort* yhb = yh + (size_t)grow * D + ko;
  const ushort* ylb = yl + (size_t)grow * D + ko;
  const int sa = srow * 40 + ko;

  float4 f0, f1;
  uint4 r2, r3;
#define LOADP(p)                                  \
  {                                               \
    f0 = *(const float4*)(Ag + (p) * 32);         \
    f1 = *(const float4*)(Ag + (p) * 32 + 4);     \
    r2 = *(const uint4*)(yhb + (p) * 32);         \
    r3 = *(const uint4*)(ylb + (p) * 32);         \
  }
#define STOREB(buf)                                                        \
  {                                                                        \
    ushort h0, l0, h1, l1, h2, l2, h3, l3;                                 \
    ushort* Bp = &As[(buf) * 10240];                                       \
    bf16split(f0.x, h0, l0); bf16split(f0.y, h1, l1);                      \
    bf16split(f0.z, h2, l2); bf16split(f0.w, h3, l3);                      \
    *(ushort4*)&Bp[sa] = make_ushort4(h0, h1, h2, h3);                     \
    *(ushort4*)&Bp[2560 + sa] = make_ushort4(l0, l1, l2, l3);              \
    bf16split(f1.x, h0, l0); bf16split(f1.y, h1, l1);                      \
    bf16split(f1.z, h2, l2); bf16split(f1.w, h3, l3);                      \
    *(ushort4*)&Bp[sa + 4] = make_ushort4(h0, h1, h2, h3);                 \
    *(ushort4*)&Bp[2560 + sa + 4] = make_ushort4(l0, l1, l2, l3);          \
    *(uint4*)&Bp[5120 + sa] = r2;                                          \
    *(uint4*)&Bp[7680 + sa] = r3;                                          \
  }

  LOADP(0);
  STOREB(0);
  LOADP(1);
  __syncthreads();

  for (int p = 0; p < 4; ++p) {
    if (p < 3) STOREB((p + 1) & 1);  // regs hold pass p+1; buf^1 free since
    if (p < 2) LOADP(p + 2);         // last barrier. prefetch p+2 under MFMAs.
    const ushort* Ab = &As[(p & 1) * 10240];
#pragma unroll
    for (int j = 0; j < 2; ++j) {
      const ushort* g1 = wt + (size_t)(w * 32 + j * 16 + m) * 128 + p * 32 + quad * 8;
      const short8 w1h = *(const short8*)g1;
      const short8 w1l = *(const short8*)(g1 + 16384);
      const short8 w2h = *(const short8*)(g1 + 32768);
      const short8 w2l = *(const short8*)(g1 + 49152);
#pragma unroll
      for (int i = 0; i < 4; ++i) {
        const int r = (i * 16 + m) * 40 + quad * 8;
        const short8 a1h = *(const short8*)&Ab[r];
        const short8 a1l = *(const short8*)&Ab[2560 + r];
        const short8 a2h = *(const short8*)&Ab[5120 + r];
        const short8 a2l = *(const short8*)&Ab[7680 + r];
        floatx4 c = acc[i][j];
        c = __builtin_amdgcn_mfma_f32_16x16x32_bf16(a1h, w1h, c, 0, 0, 0);
        c = __builtin_amdgcn_mfma_f32_16x16x32_bf16(a1h, w1l, c, 0, 0, 0);
        c = __builtin_amdgcn_mfma_f32_16x16x32_bf16(a1l, w1h, c, 0, 0, 0);
        c = __builtin_amdgcn_mfma_f32_16x16x32_bf16(a2h, w2h, c, 0, 0, 0);
        c = __builtin_amdgcn_mfma_f32_16x16x32_bf16(a2h, w2l, c, 0, 0, 0);
        c = __builtin_amdgcn_mfma_f32_16x16x32_bf16(a2l, w2h, c, 0, 0, 0);
        acc[i][j] = c;
      }
    }
    __syncthreads();
  }
#undef LOADP
#undef STOREB

  // --- epilogue: C/D layout col=lane&15, row=quad*4+reg ---
  float bb[2], b2c[2];
#pragma unroll
  for (int j = 0; j < 2; ++j) {
    const int col = w * 32 + j * 16 + m;
    bb[j] = b1[col] + gvec[col];
    b2c[j] = b2[col];
  }
  float asum[2] = {0.f, 0.f};
#pragma unroll
  for (int i = 0; i < 4; ++i)
#pragma unroll
    for (int pp = 0; pp < 4; ++pp) {
      const int rg = row0 + i * 16 + quad * 4 + pp;
      if (rg >= n) continue;
      const float crv = cf[rg];
#pragma unroll
      for (int j = 0; j < 2; ++j) {
        const int col = w * 32 + j * 16 + m;
        float v = acc[i][j][pp] + bb[j] + crv * b2c[j];
        v = fmaxf(v, 0.f) + A[(size_t)rg * D + col];
        outH[(size_t)rg * D + col] = v;
        asum[j] += v;
      }
    }
#pragma unroll
  for (int j = 0; j < 2; ++j) {
    float v = asum[j];
    v += __shfl_xor(v, 16);
    v += __shfl_xor(v, 32);
    if (lane < 16) atomicAdd(an + w * 32 + j * 16 + m, v);
  }
}

// K3: g_new = globals + relu(concat([an, globals]) @ Wg + bg), 2-way k-split
__global__ void k_gupdate(const float* __restrict__ an, const float* __restrict__ g,
                          const float* __restrict__ Wg, const float* __restrict__ bg,
                          float* __restrict__ gout) {
  __shared__ float part[256];
  const int j = threadIdx.x & 127, half = threadIdx.x >> 7;
  float acc = 0.f;
  if (half == 0) {
    for (int k = 0; k < D; ++k) acc = fmaf(an[k], Wg[k * D + j], acc);
  } else {
    for (int k = 0; k < D; ++k) acc = fmaf(g[k], Wg[(D + k) * D + j], acc);
  }
  part[threadIdx.x] = acc;
  __syncthreads();
  if (threadIdx.x < D)
    gout[j] = g[j] + fmaxf(bg[j] + part[j] + part[j + 128], 0.f);
}

extern "C" void kernel_launch(void* const* d_in, const int* in_sizes, int n_in,
                              void* d_out, int out_size, void* d_ws, size_t ws_size,
                              hipStream_t stream) {
  const float* nodes = (const float*)d_in[0];
  const float* globals_ = (const float*)d_in[1];
  const int* senders = (const int*)d_in[2];
  const int* receivers = (const int*)d_in[3];
  const float* W1_w = (const float*)d_in[4];
  const float* W1_b = (const float*)d_in[5];
  const float* W2_w = (const float*)d_in[6];
  const float* W2_b = (const float*)d_in[7];
  const float* W3_w = (const float*)d_in[8];
  const float* W3_b = (const float*)d_in[9];
  const float* Wg_w = (const float*)d_in[10];
  const float* Wg_b = (const float*)d_in[11];
  const int N = in_sizes[0] / D;
  const int E = in_sizes[2];
  const int nbE = (E + 255) / 256;

  float* h = (float*)d_out;
  float* gout = h + (size_t)N * D;

  float* ws = (float*)d_ws;
  ushort* yh = (ushort*)ws;                    // N*128 ushorts
  ushort* yl = yh + (size_t)N * D;             // N*128 ushorts
  int* cnt_send = (int*)(yl + (size_t)N * D);  // N   (zeroed)
  int* cnt_recv = cnt_send + N;                // N   (zeroed; becomes c_r float)
  float* an = (float*)(cnt_recv + N);          // D   (zeroed)
  int* ovfn = (int*)(an + D);                  // 1 (+63 pad, zeroed)
  float* gvec = (float*)(ovfn + 64);           // D
  int* srtp = (int*)(gvec + D);                // N*MAXDEG direct CSR
  int* ovf = srtp + (size_t)N * MAXDEG;        // 2*OVFCAP
  ushort* wt = (ushort*)(ovf + 2 * OVFCAP);    // 128 KB split weights

  // one memset covers cnt_send, cnt_recv, an, ovfn(+pad)
  (void)hipMemsetAsync(cnt_send, 0, (size_t)(2 * N + D + 64) * sizeof(int), stream);

  hipLaunchKernelGGL(k_front, dim3(nbE + 1 + 128), dim3(256), 0, stream,
                     senders, receivers, cnt_send, cnt_recv, srtp, ovf, ovfn,
                     E, nbE, globals_, W3_w, W3_b, gvec, W1_w, W2_w, wt);
  hipLaunchKernelGGL(k_agg, dim3(AGGB), dim3(256), 0, stream,
                     nodes, cnt_recv, cnt_send, srtp, ovf, ovfn, yh, yl, N);
  hipLaunchKernelGGL(k_gemm, dim3((N + 63) / 64), dim3(256), 0, stream,
                     nodes, yh, yl, wt, W1_b, W2_b, gvec,
                     (const float*)cnt_recv, h, an, N);
  hipLaunchKernelGGL(k_gupdate, dim3(1), dim3(256), 0, stream, an, globals_,
                     Wg_w, Wg_b, gout);
}